// Round 15
// baseline (317.227 us; speedup 1.0000x reference)
//
#include <hip/hip_runtime.h>
#include <hip/hip_bf16.h>

#define BB 4
#define TT 1024
#define DM 1024
#define HH 16

typedef __attribute__((ext_vector_type(8))) short short8;
typedef __attribute__((ext_vector_type(4))) short short4v;
typedef __attribute__((ext_vector_type(4))) float f32x4;
typedef __hip_bfloat16 bf16;
typedef unsigned char u8;

__device__ __forceinline__ f32x4 mfma16(short8 a, short8 b, f32x4 c) {
  return __builtin_amdgcn_mfma_f32_16x16x32_bf16(a, b, c, 0, 0, 0);
}
__device__ __forceinline__ f32x4 mfma8(long a, long b, f32x4 c) {
  return __builtin_amdgcn_mfma_f32_16x16x32_fp8_fp8(a, b, c, 0, 0, 0);
}

// ---------------------------------------------------------------------------
// x fp32 -> bf16, 8 elems/thread. grid 2048.
// ---------------------------------------------------------------------------
__global__ __launch_bounds__(256) void xb_kernel(
    const float* __restrict__ x, bf16* __restrict__ xb) {
  const size_t i = ((size_t)blockIdx.x * 256 + threadIdx.x) * 8;
  bf16 tmp[8];
#pragma unroll
  for (int j = 0; j < 8; ++j) tmp[j] = __float2bfloat16(x[i + j]);
  *(short8*)(xb + i) = *(const short8*)tmp;
}

// ---------------------------------------------------------------------------
// pack pos (u16, low) + mask (top 16 bits of fp32, high) into one u32.
// ---------------------------------------------------------------------------
__global__ __launch_bounds__(256) void pack_pm_kernel(
    const int* __restrict__ pos, const float* __restrict__ maskp,
    unsigned* __restrict__ pm) {
  const size_t i = (size_t)blockIdx.x * 256 + threadIdx.x;
  const unsigned mb = __float_as_uint(maskp[i]) & 0xffff0000u;
  pm[i] = mb | (unsigned)pos[i];
}

// ---------------------------------------------------------------------------
// W_{Q,K,V} fp32 [16][64 d][64 e] -> Wt bf16 [3][16][64 e][64 d] (transposed)
// ---------------------------------------------------------------------------
__global__ __launch_bounds__(256) void prep_w_kernel(
    const float* __restrict__ WQ, const float* __restrict__ WK,
    const float* __restrict__ WV, bf16* __restrict__ Wt) {
  __shared__ bf16 tl[64][72];
  const int h = blockIdx.x, m = blockIdx.y;
  const float* W = (m == 0 ? WQ : (m == 1 ? WK : WV)) + h * 4096;
  const int tid = threadIdx.x;
  const int r = tid >> 2, c = (tid & 3) * 16;
#pragma unroll
  for (int i = 0; i < 16; ++i)
    tl[r][c + i] = __float2bfloat16(W[r * 64 + c + i]);
  __syncthreads();
  bf16* o = Wt + ((size_t)(m * 16 + h) * 64 + r) * 64 + c;
#pragma unroll
  for (int i = 0; i < 16; ++i) o[i] = tl[c + i][r];
}

// ---------------------------------------------------------------------------
// prep: posK fp32 [2047][64] -> fp8 e4m3 [2048][64] (row 2047 zeroed)
// ---------------------------------------------------------------------------
__global__ __launch_bounds__(256) void prep_posk8_kernel(
    const float* __restrict__ posK, u8* __restrict__ posK8) {
  const int idx = (blockIdx.x * 256 + threadIdx.x) * 2;
  const int p = idx >> 6, d = idx & 63;
  const float v0 = (p < 2047) ? posK[(size_t)p * 64 + d] : 0.f;
  const float v1 = (p < 2047) ? posK[(size_t)p * 64 + d + 1] : 0.f;
  const int pk = __builtin_amdgcn_cvt_pk_fp8_f32(v0, v1, 0, false);
  *(unsigned short*)(posK8 + idx) = (unsigned short)(pk & 0xffff);
}

// ---------------------------------------------------------------------------
// prep: WzT bf16 [n][k] = Wz fp32 [k][n]
// ---------------------------------------------------------------------------
__global__ __launch_bounds__(256) void trans_wz_kernel(
    const float* __restrict__ Wz, bf16* __restrict__ WzT) {
  __shared__ bf16 tile[64][72];
  const int k0 = blockIdx.y * 64, n0 = blockIdx.x * 64;
  const int tid = threadIdx.x;
  const int r = tid >> 2, c = (tid & 3) * 16;
  const float* s = Wz + (size_t)(k0 + r) * 1024 + n0 + c;
#pragma unroll
  for (int i = 0; i < 16; ++i) tile[r][c + i] = __float2bfloat16(s[i]);
  __syncthreads();
  const int n = tid >> 2;
  bf16* o = WzT + (size_t)(n0 + n) * 1024 + k0 + c;
#pragma unroll
  for (int i = 0; i < 16; ++i) o[i] = tile[c + i][n];
}

// ---------------------------------------------------------------------------
// transpose V: [bh][1024][64] bf16 -> Vt [bh][64][1024] bf16
// ---------------------------------------------------------------------------
__global__ __launch_bounds__(256) void trans_v_kernel(
    const bf16* __restrict__ src, bf16* __restrict__ dst) {
  __shared__ bf16 tile[64][72];
  const int bh = blockIdx.y, t0 = blockIdx.x * 64;
  const int tid = threadIdx.x;
  const int r = tid >> 2, c = (tid & 3) * 16;
  const bf16* s = src + ((size_t)bh * TT + t0 + r) * 64 + c;
  *(short8*)(&tile[r][c]) = *(const short8*)(s);
  *(short8*)(&tile[r][c + 8]) = *(const short8*)(s + 8);
  __syncthreads();
  const int d = tid >> 2;
  bf16* o = dst + ((size_t)bh * 64 + d) * TT + t0 + c;
#pragma unroll
  for (int i = 0; i < 16; ++i) o[i] = tile[c + i][d];
}

// ---------------------------------------------------------------------------
// QKV projection via MFMA. Emits Q8/K8 (fp8 e4m3) + V (bf16).
// ---------------------------------------------------------------------------
__global__ __launch_bounds__(256) void qkv_mfma_kernel(
    const bf16* __restrict__ xb, const bf16* __restrict__ Wt,
    u8* __restrict__ Q8, u8* __restrict__ K8, bf16* __restrict__ Vg) {
  __shared__ __align__(16) bf16 xs[64 * 72];
  const int bh = blockIdx.y;
  const int b = bh >> 4, h = bh & 15;
  const int t0 = blockIdx.x * 64;
  const int tid = threadIdx.x;
  const int w = tid >> 6, lane = tid & 63, l15 = lane & 15, hi = lane >> 4;

  {
    const int r = tid >> 2, c = (tid & 3) * 16;
    const bf16* src = xb + ((size_t)b * TT + t0 + r) * DM + h * 64 + c;
    *(short8*)(xs + r * 72 + c) = *(const short8*)(src);
    *(short8*)(xs + r * 72 + c + 8) = *(const short8*)(src + 8);
  }
  __syncthreads();

  f32x4 aQ[4] = {{0.f, 0.f, 0.f, 0.f}, {0.f, 0.f, 0.f, 0.f},
                 {0.f, 0.f, 0.f, 0.f}, {0.f, 0.f, 0.f, 0.f}};
  f32x4 aK[4] = {{0.f, 0.f, 0.f, 0.f}, {0.f, 0.f, 0.f, 0.f},
                 {0.f, 0.f, 0.f, 0.f}, {0.f, 0.f, 0.f, 0.f}};
  f32x4 aV[4] = {{0.f, 0.f, 0.f, 0.f}, {0.f, 0.f, 0.f, 0.f},
                 {0.f, 0.f, 0.f, 0.f}, {0.f, 0.f, 0.f, 0.f}};
  const bf16* WtQ = Wt + (size_t)h * 4096;
  const bf16* WtK = Wt + (size_t)(16 + h) * 4096;
  const bf16* WtV = Wt + (size_t)(32 + h) * 4096;
#pragma unroll
  for (int kc = 0; kc < 2; ++kc) {
    const short8 a =
        *(const short8*)(xs + (w * 16 + l15) * 72 + kc * 32 + hi * 8);
#pragma unroll
    for (int nt = 0; nt < 4; ++nt) {
      const size_t wo = (size_t)(nt * 16 + l15) * 64 + kc * 32 + hi * 8;
      aQ[nt] = mfma16(a, *(const short8*)(WtQ + wo), aQ[nt]);
      aK[nt] = mfma16(a, *(const short8*)(WtK + wo), aK[nt]);
      aV[nt] = mfma16(a, *(const short8*)(WtV + wo), aV[nt]);
    }
  }
  const int t = t0 + w * 16 + hi * 4;
#pragma unroll
  for (int nt = 0; nt < 4; ++nt) {
#pragma unroll
    for (int j = 0; j < 4; ++j) {
      const size_t o = ((size_t)bh * TT + t + j) * 64 + nt * 16 + l15;
      Vg[o] = __float2bfloat16(aV[nt][j]);
    }
    const size_t o0 = ((size_t)bh * TT + t) * 64 + nt * 16 + l15;
    {
      const int p01 = __builtin_amdgcn_cvt_pk_fp8_f32(aQ[nt][0], aQ[nt][1], 0, false);
      const int p23 = __builtin_amdgcn_cvt_pk_fp8_f32(aQ[nt][2], aQ[nt][3], 0, false);
      Q8[o0] = (u8)(p01 & 0xff);
      Q8[o0 + 64] = (u8)((p01 >> 8) & 0xff);
      Q8[o0 + 128] = (u8)(p23 & 0xff);
      Q8[o0 + 192] = (u8)((p23 >> 8) & 0xff);
    }
    {
      const int p01 = __builtin_amdgcn_cvt_pk_fp8_f32(aK[nt][0], aK[nt][1], 0, false);
      const int p23 = __builtin_amdgcn_cvt_pk_fp8_f32(aK[nt][2], aK[nt][3], 0, false);
      K8[o0] = (u8)(p01 & 0xff);
      K8[o0 + 64] = (u8)((p01 >> 8) & 0xff);
      K8[o0 + 128] = (u8)(p23 & 0xff);
      K8[o0 + 192] = (u8)((p23 >> 8) & 0xff);
    }
  }
}

// ---------------------------------------------------------------------------
// Fused score kernel v11: 512 threads / 8 waves (2 waves/SIMD), 64 q-rows.
//  Waves = (kg in {0,1} k-halves) x (w in {0..3}).
//  QP phase: 128 p-tiles / 8 waves. k-loop: kg group owns 512 k; per 64-k
//  tile wave (kg,w) scores the 16-k slice w for all 64 q, barrier, then PV
//  for d-tile w over the full tile (cross-wave P read), barrier.
//  Same VMEM bytes as v10; doubles waves/SIMD; halves per-wave MFMA.
// grid (64 bh, 4 qt), block 512, 1 block/CU (150.8 KB LDS).
// ---------------------------------------------------------------------------
#define QP8_S 2052
#define PSM_S 68

__global__ __launch_bounds__(512, 1) void score_pv_kernel(
    const u8* __restrict__ Q8,
    const u8* __restrict__ K8,
    const u8* __restrict__ posK8,
    const bf16* __restrict__ Vt,
    const unsigned* __restrict__ pm,   // packed mask|pos
    bf16* __restrict__ Pws,        // [256 qlocal][64 bh][1024 k]
    float* __restrict__ l_ws,      // [64 bh][1024 q]
    float* __restrict__ ctxU,      // [b][t][1024] fp32 unnormalized
    int slab) {
  __shared__ __align__(16) u8 QPsh[64 * QP8_S];        // 131328 B
  __shared__ __align__(16) bf16 Psm[2][64 * PSM_S];    // 17408 B (per-kg)
  __shared__ float lred[8][64];                        // 2048 B

  const int bh = blockIdx.x;
  const int qt = blockIdx.y;           // 0..3
  const int qlocal0 = qt * 64;
  const int qg0 = slab * 256 + qlocal0;
  const int tid = threadIdx.x;
  const int w8 = tid >> 6;             // 0..7
  const int kg = w8 >> 2;              // 0..1 (k-half)
  const int w = w8 & 3;                // 0..3 (k-slice / d-tile)
  const int lane = tid & 63;
  const int l15 = lane & 15;
  const int hi = lane >> 4;
  const int ltid = tid & 255;          // thread id within kg group

  // Q fp8 fragments for 4 q-halves
  long aqA[4], aqB[4];
#pragma unroll
  for (int h = 0; h < 4; ++h) {
    const u8* Qrow = Q8 + ((size_t)bh * TT + qg0 + h * 16 + l15) * 64;
    aqA[h] = *(const long*)(Qrow + hi * 8);
    aqB[h] = *(const long*)(Qrow + 32 + hi * 8);
  }

  // ---- QP phase: wave w8 covers p-tiles w8*16 .. w8*16+15 (2-stage pipe)
  {
    const u8* Kp0 = posK8 + (size_t)(w8 * 16 * 16 + l15) * 64;
    long qb0 = *(const long*)(Kp0 + hi * 8);
    long qb1 = *(const long*)(Kp0 + 32 + hi * 8);
    for (int i = 0; i < 16; ++i) {
      const int pt = w8 * 16 + i;
      const long cb0 = qb0, cb1 = qb1;
      {
        const int ptn = w8 * 16 + ((i + 1) & 15);
        const u8* Kpn = posK8 + (size_t)(ptn * 16 + l15) * 64;
        qb0 = *(const long*)(Kpn + hi * 8);
        qb1 = *(const long*)(Kpn + 32 + hi * 8);
      }
      const int off = pt * 16 + l15;
#pragma unroll
      for (int h = 0; h < 4; ++h) {
        f32x4 a4 = {0.f, 0.f, 0.f, 0.f};
        a4 = mfma8(aqA[h], cb0, a4);
        a4 = mfma8(aqB[h], cb1, a4);
        const int p01 = __builtin_amdgcn_cvt_pk_fp8_f32(a4[0], a4[1], 0, false);
        const int p23 = __builtin_amdgcn_cvt_pk_fp8_f32(a4[2], a4[3], 0, false);
        const int qr = h * 16 + hi * 4;
        QPsh[(qr + 0) * QP8_S + off] = (u8)(p01 & 0xff);
        QPsh[(qr + 1) * QP8_S + off] = (u8)((p01 >> 8) & 0xff);
        QPsh[(qr + 2) * QP8_S + off] = (u8)(p23 & 0xff);
        QPsh[(qr + 3) * QP8_S + off] = (u8)((p23 >> 8) & 0xff);
      }
    }
  }
  __syncthreads();

  // ---- k-loop: kg group owns k in [kg*512, kg*512+512), 8 tiles of 64.
  // wave (kg,w): scores for k-slice kk = k0 + w*16 + l15; PV for d-tile w.
  f32x4 acc[4] = {{0.f, 0.f, 0.f, 0.f}, {0.f, 0.f, 0.f, 0.f},
                  {0.f, 0.f, 0.f, 0.f}, {0.f, 0.f, 0.f, 0.f}};
  float lp[16];
#pragma unroll
  for (int j = 0; j < 16; ++j) lp[j] = 0.f;
  const int kb = kg * 512;
  const int ksl = w * 16 + l15;  // k-slice offset within tile
  const u8* K8bh = K8 + (size_t)bh * TT * 64;
  const bf16* Vtrow = Vt + ((size_t)bh * 64 + w * 16 + l15) * TT;
  bf16* PsmG = &Psm[kg][0];

  // prologue: stage tile 0 operands
  long nb0 = *(const long*)(K8bh + (size_t)(kb + ksl) * 64 + hi * 8);
  long nb1 = *(const long*)(K8bh + (size_t)(kb + ksl) * 64 + 32 + hi * 8);
  short8 nv0 = *(const short8*)(Vtrow + kb + hi * 8);
  short8 nv1 = *(const short8*)(Vtrow + kb + 32 + hi * 8);
  unsigned npm[16];
#pragma unroll
  for (int h = 0; h < 4; ++h)
#pragma unroll
    for (int j = 0; j < 4; ++j)
      npm[h * 4 + j] =
          pm[(size_t)(qg0 + h * 16 + hi * 4 + j) * TT + kb + ksl];

  for (int it = 0; it < 8; ++it) {
    const int k0 = kb + it * 64;
    const long cb0 = nb0, cb1 = nb1;
    const short8 cv0 = nv0, cv1 = nv1;
    unsigned cpm[16];
#pragma unroll
    for (int j = 0; j < 16; ++j) cpm[j] = npm[j];
    {
      const int k0n = kb + ((it + 1) & 7) * 64;
      nb0 = *(const long*)(K8bh + (size_t)(k0n + ksl) * 64 + hi * 8);
      nb1 = *(const long*)(K8bh + (size_t)(k0n + ksl) * 64 + 32 + hi * 8);
      nv0 = *(const short8*)(Vtrow + k0n + hi * 8);
      nv1 = *(const short8*)(Vtrow + k0n + 32 + hi * 8);
#pragma unroll
      for (int h = 0; h < 4; ++h)
#pragma unroll
        for (int j = 0; j < 4; ++j)
          npm[h * 4 + j] =
              pm[(size_t)(qg0 + h * 16 + hi * 4 + j) * TT + k0n + ksl];
    }
    // scores: 4 q-halves x this wave's 16-k slice
#pragma unroll
    for (int h = 0; h < 4; ++h) {
      f32x4 s = {0.f, 0.f, 0.f, 0.f};
      s = mfma8(aqA[h], cb0, s);
      s = mfma8(aqB[h], cb1, s);
#pragma unroll
      for (int j = 0; j < 4; ++j) {
        const int q = h * 16 + hi * 4 + j;
        const unsigned pmv = cpm[h * 4 + j];
        const float qp = __builtin_amdgcn_cvt_f32_fp8(
            (int)QPsh[q * QP8_S + (pmv & 0xffffu)], 0);
        const float sv =
            (s[j] + qp + __uint_as_float(pmv & 0xffff0000u)) * 0.125f;
        const float pe = __expf(sv);
        lp[h * 4 + j] += pe;
        PsmG[q * PSM_S + ksl] = __float2bfloat16(pe);
      }
    }
    __syncthreads();  // P complete for both kg tiles
    // Pws store: kg group stores its own 64q x 64k tile
    {
      const int r = ltid >> 2, c = (ltid & 3) * 16;
      *(short8*)(Pws + ((size_t)(qlocal0 + r) * 64 + bh) * TT + k0 + c) =
          *(const short8*)(PsmG + r * PSM_S + c);
      *(short8*)(Pws + ((size_t)(qlocal0 + r) * 64 + bh) * TT + k0 + c + 8) =
          *(const short8*)(PsmG + r * PSM_S + c + 8);
    }
    // PV: wave's d-tile, 4 q-halves, full 64-k tile (cross-wave P read)
#pragma unroll
    for (int h = 0; h < 4; ++h) {
      const short8 pa0 =
          *(const short8*)(PsmG + (h * 16 + l15) * PSM_S + hi * 8);
      acc[h] = mfma16(pa0, cv0, acc[h]);
      const short8 pa1 =
          *(const short8*)(PsmG + (h * 16 + l15) * PSM_S + 32 + hi * 8);
      acc[h] = mfma16(pa1, cv1, acc[h]);
    }
    __syncthreads();  // P reads done before next-iter overwrite
  }

  // ---- epilogue: reduce l across 8 waves; ctx across kg pairs
#pragma unroll
  for (int j = 0; j < 16; ++j) {
    float v = lp[j];
    v += __shfl_xor(v, 1);
    v += __shfl_xor(v, 2);
    v += __shfl_xor(v, 4);
    v += __shfl_xor(v, 8);
    lp[j] = v;
  }
  if (l15 == 0) {
#pragma unroll
    for (int h = 0; h < 4; ++h)
#pragma unroll
      for (int j = 0; j < 4; ++j)
        lred[w8][h * 16 + hi * 4 + j] = lp[h * 4 + j];
  }
  float* red = (float*)QPsh;  // [2 kg][64 q][68] floats = 34.8 KB
#pragma unroll
  for (int h = 0; h < 4; ++h)
#pragma unroll
    for (int j = 0; j < 4; ++j)
      red[(kg * 64 + h * 16 + hi * 4 + j) * PSM_S + w * 16 + l15] = acc[h][j];
  __syncthreads();
  if (tid < 64) {
    float l = 0.f;
#pragma unroll
    for (int ww = 0; ww < 8; ++ww) l += lred[ww][tid];
    l_ws[(size_t)bh * TT + qg0 + tid] = l;
  }
  {
    const int b = bh >> 4, h16 = bh & 15;
    for (int i = tid; i < 4096; i += 512) {
      const int q = i >> 6, d = i & 63;
      ctxU[((size_t)b * TT + qg0 + q) * DM + h16 * 64 + d] =
          red[q * PSM_S + d] + red[(64 + q) * PSM_S + d];
    }
  }
}

// ---------------------------------------------------------------------------
// PV partial kernel (k-split x4): grid (256 q, 4 ks), block 256.
// ---------------------------------------------------------------------------
#define PVT_S 72
__global__ __launch_bounds__(256) void pv_part_kernel(
    const bf16* __restrict__ Pws,
    const float* __restrict__ posV,
    const unsigned* __restrict__ pm,
    float* __restrict__ PP,   // [4][256][64][64] fp32
    int slab) {
  __shared__ __align__(16) bf16 PVt[2][64 * PVT_S];
  __shared__ unsigned short possh[256];

  const int qlocal = blockIdx.x;
  const int q = slab * 256 + qlocal;
  const int ks = blockIdx.y;
  const int kbase = ks * 256;
  const int tid = threadIdx.x;
  const int w = tid >> 6, lane = tid & 63, l15 = lane & 15, hi = lane >> 4;

  possh[tid] = (unsigned short)(pm[(size_t)q * TT + kbase + tid] & 0xffffu);
  __syncthreads();

  f32x4 acc[4] = {{0.f, 0.f, 0.f, 0.f}, {0.f, 0.f, 0.f, 0.f},
                  {0.f, 0.f, 0.f, 0.f}, {0.f, 0.f, 0.f, 0.f}};
  const bf16* Prow = Pws + ((size_t)qlocal * 64 + w * 16 + l15) * TT;

  for (int it = 0; it < 4; ++it) {
    const int k0 = kbase + it * 64;
    bf16* pvt = &PVt[it & 1][0];
    {
      const int kr = lane;
      const int dc = w * 16;
      const int p = possh[it * 64 + kr];
      const float* src = posV + (size_t)p * 64 + dc;
#pragma unroll
      for (int ii = 0; ii < 16; ii += 4) {
        const f32x4 v = *(const f32x4*)(src + ii);
        pvt[(dc + ii + 0) * PVT_S + kr] = __float2bfloat16(v[0]);
        pvt[(dc + ii + 1) * PVT_S + kr] = __float2bfloat16(v[1]);
        pvt[(dc + ii + 2) * PVT_S + kr] = __float2bfloat16(v[2]);
        pvt[(dc + ii + 3) * PVT_S + kr] = __float2bfloat16(v[3]);
      }
    }
    __syncthreads();
#pragma unroll
    for (int kc = 0; kc < 2; ++kc) {
      const short8 a = *(const short8*)(Prow + k0 + kc * 32 + hi * 8);
#pragma unroll
      for (int nt = 0; nt < 4; ++nt) {
        const short8 bv =
            *(const short8*)(pvt + (nt * 16 + l15) * PVT_S + kc * 32 + hi * 8);
        acc[nt] = mfma16(a, bv, acc[nt]);
      }
    }
  }

  const int bh0 = w * 16 + hi * 4;
#pragma unroll
  for (int j = 0; j < 4; ++j) {
    const int bh = bh0 + j;
    float* o = PP + (((size_t)ks * 256 + qlocal) * 64 + bh) * 64;
#pragma unroll
    for (int nt = 0; nt < 4; ++nt) o[nt * 16 + l15] = acc[nt][j];
  }
}

// ---------------------------------------------------------------------------
// Normalize: ctxB = (ctxU + sum_ks PP) / l. grid 1024, block 256.
// ---------------------------------------------------------------------------
__global__ __launch_bounds__(256) void norm_kernel(
    const float* __restrict__ PP,
    const float* __restrict__ ctxU,
    const float* __restrict__ l_ws,
    bf16* __restrict__ ctxB,
    int slab) {
  const int i4 = blockIdx.x * 256 + threadIdx.x;  // 0..262143
  const int e0 = i4 * 4;
  const int dm = e0 & 1023;
  const int qlocal = (e0 >> 10) & 255;
  const int b = e0 >> 18;
  const int h = dm >> 6, d0 = dm & 63;
  const int bh = b * 16 + h;
  const int q = slab * 256 + qlocal;

  f32x4 v = *(const f32x4*)(ctxU + ((size_t)b * TT + q) * DM + dm);
#pragma unroll
  for (int ks = 0; ks < 4; ++ks)
    v += *(const f32x4*)(PP + (((size_t)ks * 256 + qlocal) * 64 + bh) * 64 + d0);
  const float invl = 1.0f / l_ws[(size_t)bh * TT + q];
  bf16 o[4];
#pragma unroll
  for (int j = 0; j < 4; ++j) o[j] = __float2bfloat16(v[j] * invl);
  *(short4v*)(ctxB + ((size_t)b * TT + q) * DM + dm) = *(const short4v*)o;
}

// ---------------------------------------------------------------------------
// Output projection: 128x128 LDS-tiled MFMA GEMM, BK=64, 4 waves (2x2).
// ---------------------------------------------------------------------------
__global__ __launch_bounds__(256) void outproj_mfma_kernel(
    const bf16* __restrict__ A,   // [4096][1024] bf16
    const bf16* __restrict__ Bt,  // [1024 n][1024 k] bf16
    float* __restrict__ C) {
  __shared__ __align__(16) bf16 As[128 * 72];
  __shared__ __align__(16) bf16 Bs[128 * 72];
  const int n0 = blockIdx.x * 128;
  const int m0 = blockIdx.y * 128;
  const int tid = threadIdx.x;
  const int w = tid >> 6, lane = tid & 63, l15 = lane & 15, hi = lane >> 4;
  const int wm = w >> 1, wn = w & 1;

  f32x4 acc[4][4];
#pragma unroll
  for (int i = 0; i < 4; ++i)
#pragma unroll
    for (int j = 0; j < 4; ++j) acc[i][j] = (f32x4){0.f, 0.f, 0.f, 0.f};

  const int sr = tid >> 1, sc = (tid & 1) * 32;
  for (int k0 = 0; k0 < 1024; k0 += 64) {
    __syncthreads();
    {
      const bf16* as = A + (size_t)(m0 + sr) * 1024 + k0 + sc;
      const bf16* bs = Bt + (size_t)(n0 + sr) * 1024 + k0 + sc;
#pragma unroll
      for (int ii = 0; ii < 32; ii += 8) {
        *(short8*)(As + sr * 72 + sc + ii) = *(const short8*)(as + ii);
        *(short8*)(Bs + sr * 72 + sc + ii) = *(const short8*)(bs + ii);
      }
    }
    __syncthreads();
#pragma unroll
    for (int kc = 0; kc < 2; ++kc) {
      short8 a[4], b[4];
#pragma unroll
      for (int i = 0; i < 4; ++i)
        a[i] = *(const short8*)(As + (wm * 64 + i * 16 + l15) * 72 + kc * 32 +
                                hi * 8);
#pragma unroll
      for (int j = 0; j < 4; ++j)
        b[j] = *(const short8*)(Bs + (wn * 64 + j * 16 + l15) * 72 + kc * 32 +
                                hi * 8);
#pragma unroll
      for (int i = 0; i < 4; ++i)
#pragma unroll
        for (int j = 0; j < 4; ++j) acc[i][j] = mfma16(a[i], b[j], acc[i][j]);
    }
  }
#pragma unroll
  for (int i = 0; i < 4; ++i) {
#pragma unroll
    for (int jj = 0; jj < 4; ++jj) {
      const size_t row = (size_t)(m0 + wm * 64 + i * 16 + hi * 4 + jj) * 1024;
#pragma unroll
      for (int j = 0; j < 4; ++j)
        C[row + n0 + wn * 64 + j * 16 + l15] = acc[i][j][jj];
    }
  }
}

// ---------------------------------------------------------------------------
extern "C" void kernel_launch(void* const* d_in, const int* in_sizes, int n_in,
                              void* d_out, int out_size, void* d_ws,
                              size_t ws_size, hipStream_t stream) {
  const float* x = (const float*)d_in[0];
  const float* WQ = (const float*)d_in[1];
  const float* WK = (const float*)d_in[2];
  const float* WV = (const float*)d_in[3];
  const float* WZ = (const float*)d_in[4];
  const float* posK = (const float*)d_in[5];
  const float* posV = (const float*)d_in[6];
  const float* maskp = (const float*)d_in[7];
  const int* pos = (const int*)d_in[8];
  float* out = (float*)d_out;

  char* p = (char*)d_ws;
  u8* Q8 = (u8*)p;            p += (size_t)64 * 1024 * 64;      // 4 MB
  u8* K8 = (u8*)p;            p += (size_t)64 * 1024 * 64;      // 4 MB
  bf16* Vb = (bf16*)p;        p += (size_t)64 * 1024 * 64 * 2;  // 8 MB
  bf16* Vt = (bf16*)p;        p += (size_t)64 * 64 * 1024 * 2;  // 8 MB
  u8* posK8 = (u8*)p;         p += (size_t)2048 * 64;           // 128 KB
  bf16* WzT = (bf16*)p;       p += (size_t)1024 * 1024 * 2;     // 2 MB
  bf16* Pws = (bf16*)p;       p += (size_t)256 * 64 * 1024 * 2; // 32 MB
  float* l_ws = (float*)p;    p += (size_t)64 * 1024 * 4;       // 256 KB
  float* ctxU = (float*)p;    p += (size_t)4 * 1024 * 1024 * 4; // 16 MB
  bf16* ctxB = (bf16*)p;      p += (size_t)4 * 1024 * 1024 * 2; // 8 MB
  float* PP = (float*)p;      p += (size_t)4 * 256 * 64 * 64 * 4; // 16 MB
  unsigned* pm_ws = (unsigned*)p; p += (size_t)1024 * 1024 * 4;   // 4 MB

  // Aliases (dead-range reuse, safe under stream ordering):
  bf16* xb = (bf16*)ctxU;  // xb dead after qkv; ctxU written later
  bf16* Wt = ctxB;         // Wt dead after qkv; ctxB written later

  xb_kernel<<<2048, 256, 0, stream>>>(x, xb);
  pack_pm_kernel<<<4096, 256, 0, stream>>>(pos, maskp, pm_ws);
  prep_w_kernel<<<dim3(16, 3), 256, 0, stream>>>(WQ, WK, WV, Wt);
  prep_posk8_kernel<<<256, 256, 0, stream>>>(posK, posK8);
  trans_wz_kernel<<<dim3(16, 16), 256, 0, stream>>>(WZ, WzT);
  qkv_mfma_kernel<<<dim3(16, 64), 256, 0, stream>>>(xb, Wt, Q8, K8, Vb);
  trans_v_kernel<<<dim3(16, 64), 256, 0, stream>>>(Vb, Vt);

  for (int slab = 0; slab < 4; ++slab) {
    score_pv_kernel<<<dim3(64, 4), 512, 0, stream>>>(
        Q8, K8, posK8, Vt, pm_ws, Pws, l_ws, ctxU, slab);
    pv_part_kernel<<<dim3(256, 4), 256, 0, stream>>>(Pws, posV, pm_ws, PP,
                                                     slab);
    norm_kernel<<<1024, 256, 0, stream>>>(PP, ctxU, l_ws, ctxB, slab);
  }
  outproj_mfma_kernel<<<dim3(8, 32), 256, 0, stream>>>(ctxB, WzT, out);
}

// Round 16
// 272.438 us; speedup vs baseline: 1.1644x; 1.1644x over previous
//
#include <hip/hip_runtime.h>
#include <hip/hip_bf16.h>

#define BB 4
#define TT 1024
#define DM 1024
#define HH 16

typedef __attribute__((ext_vector_type(8))) short short8;
typedef __attribute__((ext_vector_type(4))) short short4v;
typedef __attribute__((ext_vector_type(4))) float f32x4;
typedef __hip_bfloat16 bf16;
typedef unsigned char u8;

__device__ __forceinline__ f32x4 mfma16(short8 a, short8 b, f32x4 c) {
  return __builtin_amdgcn_mfma_f32_16x16x32_bf16(a, b, c, 0, 0, 0);
}
__device__ __forceinline__ f32x4 mfma8(long a, long b, f32x4 c) {
  return __builtin_amdgcn_mfma_f32_16x16x32_fp8_fp8(a, b, c, 0, 0, 0);
}

// ---------------------------------------------------------------------------
// pack pos (u16, low) + mask (top 16 bits of fp32, high) into one u32.
// ---------------------------------------------------------------------------
__global__ __launch_bounds__(256) void pack_pm_kernel(
    const int* __restrict__ pos, const float* __restrict__ maskp,
    unsigned* __restrict__ pm) {
  const size_t i = (size_t)blockIdx.x * 256 + threadIdx.x;
  const unsigned mb = __float_as_uint(maskp[i]) & 0xffff0000u;
  pm[i] = mb | (unsigned)pos[i];
}

// ---------------------------------------------------------------------------
// W_{Q,K,V} fp32 [16][64 d][64 e] -> Wt bf16 [3][16][64 e][64 d] (transposed)
// ---------------------------------------------------------------------------
__global__ __launch_bounds__(256) void prep_w_kernel(
    const float* __restrict__ WQ, const float* __restrict__ WK,
    const float* __restrict__ WV, bf16* __restrict__ Wt) {
  __shared__ bf16 tl[64][72];
  const int h = blockIdx.x, m = blockIdx.y;
  const float* W = (m == 0 ? WQ : (m == 1 ? WK : WV)) + h * 4096;
  const int tid = threadIdx.x;
  const int r = tid >> 2, c = (tid & 3) * 16;
#pragma unroll
  for (int i = 0; i < 16; ++i)
    tl[r][c + i] = __float2bfloat16(W[r * 64 + c + i]);
  __syncthreads();
  bf16* o = Wt + ((size_t)(m * 16 + h) * 64 + r) * 64 + c;
#pragma unroll
  for (int i = 0; i < 16; ++i) o[i] = tl[c + i][r];
}

// ---------------------------------------------------------------------------
// prep: posK fp32 [2047][64] -> fp8 e4m3 [2048][64] (row 2047 zeroed)
// ---------------------------------------------------------------------------
__global__ __launch_bounds__(256) void prep_posk8_kernel(
    const float* __restrict__ posK, u8* __restrict__ posK8) {
  const int idx = (blockIdx.x * 256 + threadIdx.x) * 2;
  const int p = idx >> 6, d = idx & 63;
  const float v0 = (p < 2047) ? posK[(size_t)p * 64 + d] : 0.f;
  const float v1 = (p < 2047) ? posK[(size_t)p * 64 + d + 1] : 0.f;
  const int pk = __builtin_amdgcn_cvt_pk_fp8_f32(v0, v1, 0, false);
  *(unsigned short*)(posK8 + idx) = (unsigned short)(pk & 0xffff);
}

// ---------------------------------------------------------------------------
// prep: WzT bf16 [n][k] = Wz fp32 [k][n]
// ---------------------------------------------------------------------------
__global__ __launch_bounds__(256) void trans_wz_kernel(
    const float* __restrict__ Wz, bf16* __restrict__ WzT) {
  __shared__ bf16 tile[64][72];
  const int k0 = blockIdx.y * 64, n0 = blockIdx.x * 64;
  const int tid = threadIdx.x;
  const int r = tid >> 2, c = (tid & 3) * 16;
  const float* s = Wz + (size_t)(k0 + r) * 1024 + n0 + c;
#pragma unroll
  for (int i = 0; i < 16; ++i) tile[r][c + i] = __float2bfloat16(s[i]);
  __syncthreads();
  const int n = tid >> 2;
  bf16* o = WzT + (size_t)(n0 + n) * 1024 + k0 + c;
#pragma unroll
  for (int i = 0; i < 16; ++i) o[i] = tile[c + i][n];
}

// ---------------------------------------------------------------------------
// transpose V: [bh][1024][64] bf16 -> Vt [bh][64][1024] bf16
// ---------------------------------------------------------------------------
__global__ __launch_bounds__(256) void trans_v_kernel(
    const bf16* __restrict__ src, bf16* __restrict__ dst) {
  __shared__ bf16 tile[64][72];
  const int bh = blockIdx.y, t0 = blockIdx.x * 64;
  const int tid = threadIdx.x;
  const int r = tid >> 2, c = (tid & 3) * 16;
  const bf16* s = src + ((size_t)bh * TT + t0 + r) * 64 + c;
  *(short8*)(&tile[r][c]) = *(const short8*)(s);
  *(short8*)(&tile[r][c + 8]) = *(const short8*)(s + 8);
  __syncthreads();
  const int d = tid >> 2;
  bf16* o = dst + ((size_t)bh * 64 + d) * TT + t0 + c;
#pragma unroll
  for (int i = 0; i < 16; ++i) o[i] = tile[c + i][d];
}

// ---------------------------------------------------------------------------
// QKV projection via MFMA; reads x fp32 directly (xb kernel dropped).
// Emits Q8/K8 (fp8 e4m3) + V (bf16). grid (16 ttiles, 64 bh), block 256.
// ---------------------------------------------------------------------------
__global__ __launch_bounds__(256) void qkv_mfma_kernel(
    const float* __restrict__ x, const bf16* __restrict__ Wt,
    u8* __restrict__ Q8, u8* __restrict__ K8, bf16* __restrict__ Vg) {
  __shared__ __align__(16) bf16 xs[64 * 72];
  const int bh = blockIdx.y;
  const int b = bh >> 4, h = bh & 15;
  const int t0 = blockIdx.x * 64;
  const int tid = threadIdx.x;
  const int w = tid >> 6, lane = tid & 63, l15 = lane & 15, hi = lane >> 4;

  {
    const int r = tid >> 2, c = (tid & 3) * 16;
    const float* src = x + ((size_t)b * TT + t0 + r) * DM + h * 64 + c;
    bf16 tmp[16];
#pragma unroll
    for (int i = 0; i < 16; i += 4) {
      const f32x4 v = *(const f32x4*)(src + i);
      tmp[i + 0] = __float2bfloat16(v[0]);
      tmp[i + 1] = __float2bfloat16(v[1]);
      tmp[i + 2] = __float2bfloat16(v[2]);
      tmp[i + 3] = __float2bfloat16(v[3]);
    }
    *(short8*)(xs + r * 72 + c) = *(const short8*)tmp;
    *(short8*)(xs + r * 72 + c + 8) = *(const short8*)(tmp + 8);
  }
  __syncthreads();

  f32x4 aQ[4] = {{0.f, 0.f, 0.f, 0.f}, {0.f, 0.f, 0.f, 0.f},
                 {0.f, 0.f, 0.f, 0.f}, {0.f, 0.f, 0.f, 0.f}};
  f32x4 aK[4] = {{0.f, 0.f, 0.f, 0.f}, {0.f, 0.f, 0.f, 0.f},
                 {0.f, 0.f, 0.f, 0.f}, {0.f, 0.f, 0.f, 0.f}};
  f32x4 aV[4] = {{0.f, 0.f, 0.f, 0.f}, {0.f, 0.f, 0.f, 0.f},
                 {0.f, 0.f, 0.f, 0.f}, {0.f, 0.f, 0.f, 0.f}};
  const bf16* WtQ = Wt + (size_t)h * 4096;
  const bf16* WtK = Wt + (size_t)(16 + h) * 4096;
  const bf16* WtV = Wt + (size_t)(32 + h) * 4096;
#pragma unroll
  for (int kc = 0; kc < 2; ++kc) {
    const short8 a =
        *(const short8*)(xs + (w * 16 + l15) * 72 + kc * 32 + hi * 8);
#pragma unroll
    for (int nt = 0; nt < 4; ++nt) {
      const size_t wo = (size_t)(nt * 16 + l15) * 64 + kc * 32 + hi * 8;
      aQ[nt] = mfma16(a, *(const short8*)(WtQ + wo), aQ[nt]);
      aK[nt] = mfma16(a, *(const short8*)(WtK + wo), aK[nt]);
      aV[nt] = mfma16(a, *(const short8*)(WtV + wo), aV[nt]);
    }
  }
  const int t = t0 + w * 16 + hi * 4;
#pragma unroll
  for (int nt = 0; nt < 4; ++nt) {
#pragma unroll
    for (int j = 0; j < 4; ++j) {
      const size_t o = ((size_t)bh * TT + t + j) * 64 + nt * 16 + l15;
      Vg[o] = __float2bfloat16(aV[nt][j]);
    }
    const size_t o0 = ((size_t)bh * TT + t) * 64 + nt * 16 + l15;
    {
      const int p01 = __builtin_amdgcn_cvt_pk_fp8_f32(aQ[nt][0], aQ[nt][1], 0, false);
      const int p23 = __builtin_amdgcn_cvt_pk_fp8_f32(aQ[nt][2], aQ[nt][3], 0, false);
      Q8[o0] = (u8)(p01 & 0xff);
      Q8[o0 + 64] = (u8)((p01 >> 8) & 0xff);
      Q8[o0 + 128] = (u8)(p23 & 0xff);
      Q8[o0 + 192] = (u8)((p23 >> 8) & 0xff);
    }
    {
      const int p01 = __builtin_amdgcn_cvt_pk_fp8_f32(aK[nt][0], aK[nt][1], 0, false);
      const int p23 = __builtin_amdgcn_cvt_pk_fp8_f32(aK[nt][2], aK[nt][3], 0, false);
      K8[o0] = (u8)(p01 & 0xff);
      K8[o0 + 64] = (u8)((p01 >> 8) & 0xff);
      K8[o0 + 128] = (u8)(p23 & 0xff);
      K8[o0 + 192] = (u8)((p23 >> 8) & 0xff);
    }
  }
}

// ---------------------------------------------------------------------------
// Fused score kernel (v10, reverted): 64 q-rows/block, 256 threads,
// fp8 Q/K/posK, 2-stage register pipeline, wave-private d-tiles.
// grid (64 bh, 4 qt), block 256, 1 block/CU (150 KB LDS).
// ---------------------------------------------------------------------------
#define QP8_S 2052
#define PSM_S 72

__global__ __launch_bounds__(256, 1) void score_pv_kernel(
    const u8* __restrict__ Q8,
    const u8* __restrict__ K8,
    const u8* __restrict__ posK8,
    const bf16* __restrict__ Vt,
    const unsigned* __restrict__ pm,   // packed mask|pos
    bf16* __restrict__ Pws,        // [256 qlocal][64 bh][1024 k]
    float* __restrict__ l_ws,      // [64 bh][1024 q]
    float* __restrict__ ctxU,      // [b][t][1024] fp32 unnormalized
    int slab) {
  __shared__ __align__(16) u8 QPsh[64 * QP8_S];        // 131328 B
  __shared__ __align__(16) bf16 Psm[2][64 * PSM_S];    // 18432 B
  __shared__ float lred[4][64];                        // 1024 B

  const int bh = blockIdx.x;
  const int qt = blockIdx.y;           // 0..3
  const int qlocal0 = qt * 64;
  const int qg0 = slab * 256 + qlocal0;
  const int tid = threadIdx.x;
  const int w = tid >> 6;
  const int lane = tid & 63;
  const int l15 = lane & 15;
  const int hi = lane >> 4;

  // Q fp8 fragments for 4 q-halves
  long aqA[4], aqB[4];
#pragma unroll
  for (int h = 0; h < 4; ++h) {
    const u8* Qrow = Q8 + ((size_t)bh * TT + qg0 + h * 16 + l15) * 64;
    aqA[h] = *(const long*)(Qrow + hi * 8);
    aqB[h] = *(const long*)(Qrow + 32 + hi * 8);
  }

  // ---- QP phase: wave w covers p-tiles w*32..w*32+31; fp8 MFMA; fp8 store
  {
    const u8* Kp0 = posK8 + (size_t)(w * 32 * 16 + l15) * 64;
    long qb0 = *(const long*)(Kp0 + hi * 8);
    long qb1 = *(const long*)(Kp0 + 32 + hi * 8);
    for (int i = 0; i < 32; ++i) {
      const int pt = w * 32 + i;
      const long cb0 = qb0, cb1 = qb1;
      {
        const int ptn = w * 32 + ((i + 1) & 31);
        const u8* Kpn = posK8 + (size_t)(ptn * 16 + l15) * 64;
        qb0 = *(const long*)(Kpn + hi * 8);
        qb1 = *(const long*)(Kpn + 32 + hi * 8);
      }
      const int off = pt * 16 + l15;
#pragma unroll
      for (int h = 0; h < 4; ++h) {
        f32x4 a4 = {0.f, 0.f, 0.f, 0.f};
        a4 = mfma8(aqA[h], cb0, a4);
        a4 = mfma8(aqB[h], cb1, a4);
        const int p01 = __builtin_amdgcn_cvt_pk_fp8_f32(a4[0], a4[1], 0, false);
        const int p23 = __builtin_amdgcn_cvt_pk_fp8_f32(a4[2], a4[3], 0, false);
        const int qr = h * 16 + hi * 4;
        QPsh[(qr + 0) * QP8_S + off] = (u8)(p01 & 0xff);
        QPsh[(qr + 1) * QP8_S + off] = (u8)((p01 >> 8) & 0xff);
        QPsh[(qr + 2) * QP8_S + off] = (u8)(p23 & 0xff);
        QPsh[(qr + 3) * QP8_S + off] = (u8)((p23 >> 8) & 0xff);
      }
    }
  }
  __syncthreads();

  // wave w owns PV output d-tile [w*16, w*16+16) for all 64 q
  f32x4 acc[4] = {{0.f, 0.f, 0.f, 0.f}, {0.f, 0.f, 0.f, 0.f},
                  {0.f, 0.f, 0.f, 0.f}, {0.f, 0.f, 0.f, 0.f}};
  float lp[16];
#pragma unroll
  for (int j = 0; j < 16; ++j) lp[j] = 0.f;
  const int kk = w * 16 + l15;
  const u8* K8bh = K8 + (size_t)bh * TT * 64;
  const bf16* Vtrow = Vt + ((size_t)bh * 64 + w * 16 + l15) * TT;

  // prologue: stage tile 0 operands in registers
  long nb0 = *(const long*)(K8bh + (size_t)kk * 64 + hi * 8);
  long nb1 = *(const long*)(K8bh + (size_t)kk * 64 + 32 + hi * 8);
  short8 nv0 = *(const short8*)(Vtrow + hi * 8);
  short8 nv1 = *(const short8*)(Vtrow + 32 + hi * 8);
  unsigned npm[16];
#pragma unroll
  for (int h = 0; h < 4; ++h)
#pragma unroll
    for (int j = 0; j < 4; ++j)
      npm[h * 4 + j] = pm[(size_t)(qg0 + h * 16 + hi * 4 + j) * TT + kk];

  for (int it = 0; it < 16; ++it) {
    const int k0 = it * 64;
    bf16* PsmC = &Psm[it & 1][0];
    const long cb0 = nb0, cb1 = nb1;
    const short8 cv0 = nv0, cv1 = nv1;
    unsigned cpm[16];
#pragma unroll
    for (int j = 0; j < 16; ++j) cpm[j] = npm[j];
    {
      const int k0n = ((it + 1) & 15) * 64;
      nb0 = *(const long*)(K8bh + (size_t)(k0n + kk) * 64 + hi * 8);
      nb1 = *(const long*)(K8bh + (size_t)(k0n + kk) * 64 + 32 + hi * 8);
      nv0 = *(const short8*)(Vtrow + k0n + hi * 8);
      nv1 = *(const short8*)(Vtrow + k0n + 32 + hi * 8);
#pragma unroll
      for (int h = 0; h < 4; ++h)
#pragma unroll
        for (int j = 0; j < 4; ++j)
          npm[h * 4 + j] =
              pm[(size_t)(qg0 + h * 16 + hi * 4 + j) * TT + k0n + kk];
    }
    // content scores for 4 q-halves from shared fp8 K frags
#pragma unroll
    for (int h = 0; h < 4; ++h) {
      f32x4 s = {0.f, 0.f, 0.f, 0.f};
      s = mfma8(aqA[h], cb0, s);
      s = mfma8(aqB[h], cb1, s);
#pragma unroll
      for (int j = 0; j < 4; ++j) {
        const int q = h * 16 + hi * 4 + j;
        const unsigned pmv = cpm[h * 4 + j];
        const float qp = __builtin_amdgcn_cvt_f32_fp8(
            (int)QPsh[q * QP8_S + (pmv & 0xffffu)], 0);
        const float sv =
            (s[j] + qp + __uint_as_float(pmv & 0xffff0000u)) * 0.125f;
        const float pe = __expf(sv);
        lp[h * 4 + j] += pe;
        PsmC[q * PSM_S + kk] = __float2bfloat16(pe);
      }
    }
    __syncthreads();
    // store P tile (64 q x 64 k) to global, coalesced via LDS
    {
      const int r = tid >> 2, c = (tid & 3) * 16;
      *(short8*)(Pws + ((size_t)(qlocal0 + r) * 64 + bh) * TT + k0 + c) =
          *(const short8*)(PsmC + r * PSM_S + c);
      *(short8*)(Pws + ((size_t)(qlocal0 + r) * 64 + bh) * TT + k0 + c + 8) =
          *(const short8*)(PsmC + r * PSM_S + c + 8);
    }
    // PV MFMAs: wave w's d-tile, 4 q-halves, shared Vt frags (bf16)
#pragma unroll
    for (int h = 0; h < 4; ++h) {
      const short8 pa0 =
          *(const short8*)(PsmC + (h * 16 + l15) * PSM_S + hi * 8);
      acc[h] = mfma16(pa0, cv0, acc[h]);
      const short8 pa1 =
          *(const short8*)(PsmC + (h * 16 + l15) * PSM_S + 32 + hi * 8);
      acc[h] = mfma16(pa1, cv1, acc[h]);
    }
  }

  // l row-sums: reduce over l15 lanes, then across waves
#pragma unroll
  for (int j = 0; j < 16; ++j) {
    float v = lp[j];
    v += __shfl_xor(v, 1);
    v += __shfl_xor(v, 2);
    v += __shfl_xor(v, 4);
    v += __shfl_xor(v, 8);
    lp[j] = v;
  }
  __syncthreads();
  if (l15 == 0) {
#pragma unroll
    for (int h = 0; h < 4; ++h)
#pragma unroll
      for (int j = 0; j < 4; ++j) lred[w][h * 16 + hi * 4 + j] = lp[h * 4 + j];
  }
  __syncthreads();
  if (tid < 64) {
    const float l = lred[0][tid] + lred[1][tid] + lred[2][tid] + lred[3][tid];
    l_ws[(size_t)bh * TT + qg0 + tid] = l;
  }
  // ctxU scatter: wave w owns d-range [w*16, w*16+16); 64 q rows
  {
    const int b = bh >> 4, h16 = bh & 15;
#pragma unroll
    for (int h = 0; h < 4; ++h)
#pragma unroll
      for (int j = 0; j < 4; ++j) {
        const int q = h * 16 + hi * 4 + j;
        ctxU[((size_t)b * TT + qg0 + q) * DM + h16 * 64 + w * 16 + l15] =
            acc[h][j];
      }
  }
}

// ---------------------------------------------------------------------------
// PV partial kernel (k-split x2): grid (256 q, 2 ks), block 256.
// Each block covers 512 k (8 tiles); PP halves vs ks=4.
// ---------------------------------------------------------------------------
#define PVT_S 72
__global__ __launch_bounds__(256) void pv_part_kernel(
    const bf16* __restrict__ Pws,
    const float* __restrict__ posV,
    const unsigned* __restrict__ pm,
    float* __restrict__ PP,   // [2][256][64][64] fp32
    int slab) {
  __shared__ __align__(16) bf16 PVt[2][64 * PVT_S];
  __shared__ unsigned short possh[512];

  const int qlocal = blockIdx.x;
  const int q = slab * 256 + qlocal;
  const int ks = blockIdx.y;
  const int kbase = ks * 512;
  const int tid = threadIdx.x;
  const int w = tid >> 6, lane = tid & 63, l15 = lane & 15, hi = lane >> 4;

  possh[tid] = (unsigned short)(pm[(size_t)q * TT + kbase + tid] & 0xffffu);
  possh[256 + tid] =
      (unsigned short)(pm[(size_t)q * TT + kbase + 256 + tid] & 0xffffu);
  __syncthreads();

  f32x4 acc[4] = {{0.f, 0.f, 0.f, 0.f}, {0.f, 0.f, 0.f, 0.f},
                  {0.f, 0.f, 0.f, 0.f}, {0.f, 0.f, 0.f, 0.f}};
  const bf16* Prow = Pws + ((size_t)qlocal * 64 + w * 16 + l15) * TT;

  for (int it = 0; it < 8; ++it) {
    const int k0 = kbase + it * 64;
    bf16* pvt = &PVt[it & 1][0];
    {
      const int kr = lane;
      const int dc = w * 16;
      const int p = possh[it * 64 + kr];
      const float* src = posV + (size_t)p * 64 + dc;
#pragma unroll
      for (int ii = 0; ii < 16; ii += 4) {
        const f32x4 v = *(const f32x4*)(src + ii);
        pvt[(dc + ii + 0) * PVT_S + kr] = __float2bfloat16(v[0]);
        pvt[(dc + ii + 1) * PVT_S + kr] = __float2bfloat16(v[1]);
        pvt[(dc + ii + 2) * PVT_S + kr] = __float2bfloat16(v[2]);
        pvt[(dc + ii + 3) * PVT_S + kr] = __float2bfloat16(v[3]);
      }
    }
    __syncthreads();
#pragma unroll
    for (int kc = 0; kc < 2; ++kc) {
      const short8 a = *(const short8*)(Prow + k0 + kc * 32 + hi * 8);
#pragma unroll
      for (int nt = 0; nt < 4; ++nt) {
        const short8 bv =
            *(const short8*)(pvt + (nt * 16 + l15) * PVT_S + kc * 32 + hi * 8);
        acc[nt] = mfma16(a, bv, acc[nt]);
      }
    }
  }

  const int bh0 = w * 16 + hi * 4;
#pragma unroll
  for (int j = 0; j < 4; ++j) {
    const int bh = bh0 + j;
    float* o = PP + (((size_t)ks * 256 + qlocal) * 64 + bh) * 64;
#pragma unroll
    for (int nt = 0; nt < 4; ++nt) o[nt * 16 + l15] = acc[nt][j];
  }
}

// ---------------------------------------------------------------------------
// Normalize: ctxB = (ctxU + sum_ks PP) / l. grid 1024, block 256.
// ---------------------------------------------------------------------------
__global__ __launch_bounds__(256) void norm_kernel(
    const float* __restrict__ PP,
    const float* __restrict__ ctxU,
    const float* __restrict__ l_ws,
    bf16* __restrict__ ctxB,
    int slab) {
  const int i4 = blockIdx.x * 256 + threadIdx.x;  // 0..262143
  const int e0 = i4 * 4;
  const int dm = e0 & 1023;
  const int qlocal = (e0 >> 10) & 255;
  const int b = e0 >> 18;
  const int h = dm >> 6, d0 = dm & 63;
  const int bh = b * 16 + h;
  const int q = slab * 256 + qlocal;

  f32x4 v = *(const f32x4*)(ctxU + ((size_t)b * TT + q) * DM + dm);
#pragma unroll
  for (int ks = 0; ks < 2; ++ks)
    v += *(const f32x4*)(PP + (((size_t)ks * 256 + qlocal) * 64 + bh) * 64 + d0);
  const float invl = 1.0f / l_ws[(size_t)bh * TT + q];
  bf16 o[4];
#pragma unroll
  for (int j = 0; j < 4; ++j) o[j] = __float2bfloat16(v[j] * invl);
  *(short4v*)(ctxB + ((size_t)b * TT + q) * DM + dm) = *(const short4v*)o;
}

// ---------------------------------------------------------------------------
// Output projection: 128x128 LDS-tiled MFMA GEMM, BK=64, 4 waves (2x2).
// ---------------------------------------------------------------------------
__global__ __launch_bounds__(256) void outproj_mfma_kernel(
    const bf16* __restrict__ A,   // [4096][1024] bf16
    const bf16* __restrict__ Bt,  // [1024 n][1024 k] bf16
    float* __restrict__ C) {
  __shared__ __align__(16) bf16 As[128 * 72];
  __shared__ __align__(16) bf16 Bs[128 * 72];
  const int n0 = blockIdx.x * 128;
  const int m0 = blockIdx.y * 128;
  const int tid = threadIdx.x;
  const int w = tid >> 6, lane = tid & 63, l15 = lane & 15, hi = lane >> 4;
  const int wm = w >> 1, wn = w & 1;

  f32x4 acc[4][4];
#pragma unroll
  for (int i = 0; i < 4; ++i)
#pragma unroll
    for (int j = 0; j < 4; ++j) acc[i][j] = (f32x4){0.f, 0.f, 0.f, 0.f};

  const int sr = tid >> 1, sc = (tid & 1) * 32;
  for (int k0 = 0; k0 < 1024; k0 += 64) {
    __syncthreads();
    {
      const bf16* as = A + (size_t)(m0 + sr) * 1024 + k0 + sc;
      const bf16* bs = Bt + (size_t)(n0 + sr) * 1024 + k0 + sc;
#pragma unroll
      for (int ii = 0; ii < 32; ii += 8) {
        *(short8*)(As + sr * 72 + sc + ii) = *(const short8*)(as + ii);
        *(short8*)(Bs + sr * 72 + sc + ii) = *(const short8*)(bs + ii);
      }
    }
    __syncthreads();
#pragma unroll
    for (int kc = 0; kc < 2; ++kc) {
      short8 a[4], b[4];
#pragma unroll
      for (int i = 0; i < 4; ++i)
        a[i] = *(const short8*)(As + (wm * 64 + i * 16 + l15) * 72 + kc * 32 +
                                hi * 8);
#pragma unroll
      for (int j = 0; j < 4; ++j)
        b[j] = *(const short8*)(Bs + (wn * 64 + j * 16 + l15) * 72 + kc * 32 +
                                hi * 8);
#pragma unroll
      for (int i = 0; i < 4; ++i)
#pragma unroll
        for (int j = 0; j < 4; ++j) acc[i][j] = mfma16(a[i], b[j], acc[i][j]);
    }
  }
#pragma unroll
  for (int i = 0; i < 4; ++i) {
#pragma unroll
    for (int jj = 0; jj < 4; ++jj) {
      const size_t row = (size_t)(m0 + wm * 64 + i * 16 + hi * 4 + jj) * 1024;
#pragma unroll
      for (int j = 0; j < 4; ++j)
        C[row + n0 + wn * 64 + j * 16 + l15] = acc[i][j][jj];
    }
  }
}

// ---------------------------------------------------------------------------
extern "C" void kernel_launch(void* const* d_in, const int* in_sizes, int n_in,
                              void* d_out, int out_size, void* d_ws,
                              size_t ws_size, hipStream_t stream) {
  const float* x = (const float*)d_in[0];
  const float* WQ = (const float*)d_in[1];
  const float* WK = (const float*)d_in[2];
  const float* WV = (const float*)d_in[3];
  const float* WZ = (const float*)d_in[4];
  const float* posK = (const float*)d_in[5];
  const float* posV = (const float*)d_in[6];
  const float* maskp = (const float*)d_in[7];
  const int* pos = (const int*)d_in[8];
  float* out = (float*)d_out;

  char* p = (char*)d_ws;
  u8* Q8 = (u8*)p;            p += (size_t)64 * 1024 * 64;      // 4 MB
  u8* K8 = (u8*)p;            p += (size_t)64 * 1024 * 64;      // 4 MB
  bf16* Vb = (bf16*)p;        p += (size_t)64 * 1024 * 64 * 2;  // 8 MB
  bf16* Vt = (bf16*)p;        p += (size_t)64 * 64 * 1024 * 2;  // 8 MB
  u8* posK8 = (u8*)p;         p += (size_t)2048 * 64;           // 128 KB
  bf16* WzT = (bf16*)p;       p += (size_t)1024 * 1024 * 2;     // 2 MB
  bf16* Pws = (bf16*)p;       p += (size_t)256 * 64 * 1024 * 2; // 32 MB
  float* l_ws = (float*)p;    p += (size_t)64 * 1024 * 4;       // 256 KB
  float* ctxU = (float*)p;    p += (size_t)4 * 1024 * 1024 * 4; // 16 MB
  bf16* ctxB = (bf16*)p;      p += (size_t)4 * 1024 * 1024 * 2; // 8 MB
  float* PP = (float*)p;      p += (size_t)2 * 256 * 64 * 64 * 4; // 8 MB
  unsigned* pm_ws = (unsigned*)p; p += (size_t)1024 * 1024 * 4;   // 4 MB

  // Alias (dead-range reuse, safe under stream ordering):
  bf16* Wt = ctxB;  // Wt dead after qkv; ctxB written later

  pack_pm_kernel<<<4096, 256, 0, stream>>>(pos, maskp, pm_ws);
  prep_w_kernel<<<dim3(16, 3), 256, 0, stream>>>(WQ, WK, WV, Wt);
  prep_posk8_kernel<<<256, 256, 0, stream>>>(posK, posK8);
  trans_wz_kernel<<<dim3(16, 16), 256, 0, stream>>>(WZ, WzT);
  qkv_mfma_kernel<<<dim3(16, 64), 256, 0, stream>>>(x, Wt, Q8, K8, Vb);
  trans_v_kernel<<<dim3(16, 64), 256, 0, stream>>>(Vb, Vt);

  for (int slab = 0; slab < 4; ++slab) {
    score_pv_kernel<<<dim3(64, 4), 256, 0, stream>>>(
        Q8, K8, posK8, Vt, pm_ws, Pws, l_ws, ctxU, slab);
    pv_part_kernel<<<dim3(256, 2), 256, 0, stream>>>(Pws, posV, pm_ws, PP,
                                                     slab);
    norm_kernel<<<1024, 256, 0, stream>>>(PP, ctxU, l_ws, ctxB, slab);
  }
  outproj_mfma_kernel<<<dim3(8, 32), 256, 0, stream>>>(ctxB, WzT, out);
}